// Round 10
// baseline (1237.464 us; speedup 1.0000x reference)
//
#include <hip/hip_runtime.h>
#include <cstdint>

typedef _Float16 f16;
typedef f16 f16x8 __attribute__((ext_vector_type(8)));
typedef f16 f16x4 __attribute__((ext_vector_type(4)));
typedef float f32x4 __attribute__((ext_vector_type(4)));

#define GROUP_ROWS 2560   // 2401 padded to 8*320
#define VALID_ROWS 2401
#define TPG 8             // 320-row tiles per group
#define NGROUP 12

template <bool B> struct BoolC { static constexpr bool value = B; };

__device__ __forceinline__ void gll16(const void* g, void* l) {
  __builtin_amdgcn_global_load_lds((const __attribute__((address_space(1))) void*)g,
                                   (__attribute__((address_space(3))) void*)l, 16, 0, 0);
}

// ================= prep1: wtrans(all) + AB-part + Q-direct + vW1-part =================
__global__ void prep1(const float* __restrict__ gW2, const float* __restrict__ gW3,
                      const float* __restrict__ gW4, f16* __restrict__ W2t,
                      f16* __restrict__ W3t, f16* __restrict__ W4t,
                      const float* __restrict__ conv, const float* __restrict__ gW1,
                      float* __restrict__ abP,
                      const float* __restrict__ verb_emb, const float* __restrict__ role_emb,
                      const int* __restrict__ verbs, const int* __restrict__ roles,
                      float* __restrict__ Qbuf,
                      const float* __restrict__ vW1, float* __restrict__ vp) {
  __shared__ float t[32][33];
  int id = blockIdx.x;
  if (id < 11264) {
    const float* W; f16* Wt; int K, N, local;
    if (id < 1024)      { W = gW2; Wt = W2t; K = 1024; N = 1024; local = id; }
    else if (id < 3072) { W = gW3; Wt = W3t; K = 1024; N = 2048; local = id - 1024; }
    else                { W = gW4; Wt = W4t; K = 2048; N = 4096; local = id - 3072; }
    int ntn = N >> 5;
    int k0 = (local / ntn) * 32, n0 = (local % ntn) * 32;
    int tx = threadIdx.x & 31, ty = threadIdx.x >> 5;
#pragma unroll
    for (int j = 0; j < 4; ++j)
      t[ty + j * 8][tx] = W[(size_t)(k0 + ty + j * 8) * N + n0 + tx];
    __syncthreads();
#pragma unroll
    for (int j = 0; j < 4; ++j)
      Wt[(size_t)(n0 + ty + j * 8) * K + k0 + tx] = (f16)t[tx][ty + j * 8];
  } else if (id < 14400) {
    int local = id - 11264;
    int ky = local / 392, blk = local % 392;
    int nq = blk & 3, bp = blk >> 2;
    int p = bp % 49, b = bp / 49;
    int n = nq * 256 + threadIdx.x;
    int k0 = ky * 66, k1 = k0 + 66;
    if (k1 > 514) k1 = 514;
    float accA = 0.f, accB = 0.f;
    for (int k = k0; k < k1; ++k) {
      float s;
      if (k < 512) s = conv[((size_t)b * 512 + k) * 49 + p];
      else {
        int c7 = (k == 512) ? (p % 7) : (p / 7);
        s = (float)(c7 - 3) * (4.0f / 3.0f);
      }
      accA = fmaf(s, gW1[(size_t)k * 1024 + n], accA);
      accB = fmaf(s, gW1[(size_t)(514 + k) * 1024 + n], accB);
    }
    size_t base = ((size_t)ky * 98 + bp) * 2048;
    abP[base + n] = accA;
    abP[base + 1024 + n] = accB;
  } else if (id < 14448) {
    int local = id - 14400;
    int g = local >> 2, nq = local & 3;
    int b = g / 6;
    int v = verbs[b], ro = roles[g];
    int n = nq * 256 + threadIdx.x;
    const float* ve = verb_emb + (size_t)v * 512;
    const float* re = role_emb + (size_t)ro * 512;
    const float* Wc = gW1 + (size_t)1028 * 1024;
    float acc = 0.f;
#pragma unroll 4
    for (int e = 0; e < 512; ++e)
      acc = fmaf(ve[e] * re[e], Wc[(size_t)e * 1024 + n], acc);
    Qbuf[(size_t)g * 1024 + n] = acc;
  } else {
    int local = id - 14448;
    int nblk = local & 3, kc = local >> 2;
    int n = nblk * 256 + threadIdx.x;
    int k0 = kc * 392, k1 = k0 + 392;
    if (k1 > 25088) k1 = 25088;
    float a0 = 0.f, a1 = 0.f;
#pragma unroll 4
    for (int k = k0; k < k1; ++k) {
      float w = vW1[(size_t)k * 1024 + n];
      a0 = fmaf(conv[k], w, a0);
      a1 = fmaf(conv[25088 + k], w, a1);
    }
    vp[((size_t)kc * 2 + 0) * 1024 + n] = a0;
    vp[((size_t)kc * 2 + 1) * 1024 + n] = a1;
  }
}

// ================= prep2: AB-fin + vW1-fin =================
__global__ void prep2(const float* __restrict__ abP, float* __restrict__ A,
                      float* __restrict__ Bm, const float* __restrict__ vp,
                      const float* __restrict__ vb1, float* __restrict__ v1b) {
  int id = blockIdx.x;
  if (id < 784) {
    int idx = id * 256 + threadIdx.x;
    if (idx >= 98 * 2048) return;
    int bp = idx >> 11, rem = idx & 2047;
    float s = 0.f;
#pragma unroll
    for (int ky = 0; ky < 8; ++ky) s += abP[((size_t)ky * 98 + bp) * 2048 + rem];
    if (rem < 1024) A[(size_t)bp * 1024 + rem] = s;
    else Bm[(size_t)bp * 1024 + (rem - 1024)] = s;
  } else {
    int idx = (id - 784) * 256 + threadIdx.x;
    int m = idx >> 10, n = idx & 1023;
    float s = vb1[n];
#pragma unroll 4
    for (int kc = 0; kc < 64; ++kc) s += vp[((size_t)kc * 2 + m) * 1024 + n];
    v1b[idx] = s > 0.f ? s : 0.f;
  }
}

// ---------------- h1[row][k] = relu(A[b][j] + Bm[b][i] + Q[g] + gb1) as fp16 ----------------
__global__ void build_h1(const float* __restrict__ A, const float* __restrict__ Bm,
                         const float* __restrict__ Q, const float* __restrict__ gb1,
                         f16* __restrict__ h1, int g0) {
  int rc = blockIdx.x;
  int gl = rc / GROUP_ROWS;
  int li = rc % GROUP_ROWS;
  int g = g0 + gl;
  int b = g / 6;
  int kk = threadIdx.x * 4;
  f16x4* dst = (f16x4*)(h1 + (size_t)rc * 1024 + kk);
  if (li >= VALID_ROWS) {
    f16x4 z = {(f16)0.f, (f16)0.f, (f16)0.f, (f16)0.f};
    *dst = z;
    return;
  }
  int i = li / 49, j = li % 49;
  const float4 a = *(const float4*)(A + ((size_t)b * 49 + j) * 1024 + kk);
  const float4 bb = *(const float4*)(Bm + ((size_t)b * 49 + i) * 1024 + kk);
  const float4 q = *(const float4*)(Q + (size_t)g * 1024 + kk);
  const float4 bi = *(const float4*)(gb1 + kk);
  float v0 = a.x + bb.x + q.x + bi.x;
  float v1 = a.y + bb.y + q.y + bi.y;
  float v2 = a.z + bb.z + q.z + bi.z;
  float v3 = a.w + bb.w + q.w + bi.w;
  f16x4 r;
  r.x = (f16)(v0 > 0.f ? v0 : 0.f);
  r.y = (f16)(v1 > 0.f ? v1 : 0.f);
  r.z = (f16)(v2 > 0.f ? v2 : 0.f);
  r.w = (f16)(v3 > 0.f ? v3 : 0.f);
  *dst = r;
}

// ================= 320x256 8-phase fp16 MFMA GEMM (BM=320 to cut staging bytes/FLOP) =================
// 8 waves (2M x 4N), wave tile 160x64 (10 mf). LDS 144KB: A 2x40960, B 2x32768.
// Phases carry mf-sets {3,3,2,2}. Single bF set reloaded at P3/P7 POST.
// Per-wave vmcnt: WV4 at P3/P7 drains prev-B + current-A for every wave.
#define WV4 asm volatile("s_waitcnt vmcnt(4)" ::: "memory")
#define WV0 asm volatile("s_waitcnt vmcnt(0)" ::: "memory")

#define LDSA(buf, mf, cc) (*(const f16x8*)(ldsc + (buf)*40960 + arow + (mf)*2048 + (cc)*16))
#define LDSB(buf, nf, cc) (*(const f16x8*)(ldsc + 81920 + (buf)*32768 + brow + (nf)*2048 + (cc)*16))

#define LOADB(buf) { \
  bF[0][0] = LDSB(buf, 0, c0); bF[0][1] = LDSB(buf, 0, c1); \
  bF[1][0] = LDSB(buf, 1, c0); bF[1][1] = LDSB(buf, 1, c1); \
  bF[2][0] = LDSB(buf, 2, c0); bF[2][1] = LDSB(buf, 2, c1); \
  bF[3][0] = LDSB(buf, 3, c0); bF[3][1] = LDSB(buf, 3, c1); }

// A tile 320 rows: rows [0,128) in part0; rows [128,320) in part1 (waves 0-3 carry 256-319)
#define STAGE_A0(t) { \
  const f16* _g = Aglo + (long)(t) * 64; \
  char* _l = ldsc + ((t)&1)*40960 + wave*2048; \
  gll16(_g, _l); gll16(_g + 8L*K, _l + 1024); }

#define STAGE_A1(t) { \
  const f16* _g = Aglo + (long)(t) * 64; \
  char* _l = ldsc + ((t)&1)*40960 + wave*2048; \
  gll16(_g + 128L*K, _l + 16384); gll16(_g + 136L*K, _l + 17408); \
  if (wave < 4) { gll16(_g + 256L*K, _l + 32768); gll16(_g + 264L*K, _l + 33792); } }

#define STAGE_B(t, h) { \
  const f16* _g = Bglo + (long)(h) * (128L * K) + (long)(t) * 64; \
  char* _l = ldsc + 81920 + ((t)&1)*32768 + ((h)*128 + wave*16)*128; \
  gll16(_g, _l); gll16(_g + 8L*K, _l + 1024); }

#define PHASE_MF(buf, MF0, NMF, STG, WT, POST) { \
  f16x8 aF[3][2]; \
  _Pragma("unroll") \
  for (int j = 0; j < (NMF); ++j) { \
    aF[j][0] = LDSA(buf, (MF0) + j, c0); \
    aF[j][1] = LDSA(buf, (MF0) + j, c1); \
  } \
  STG; \
  WT; \
  __builtin_amdgcn_s_barrier(); \
  __builtin_amdgcn_s_setprio(1); \
  _Pragma("unroll") \
  for (int j = 0; j < (NMF); ++j) { \
    _Pragma("unroll") \
    for (int nf = 0; nf < 4; ++nf) { \
      acc[(MF0)+j][nf] = __builtin_amdgcn_mfma_f32_16x16x32_f16(aF[j][0], bF[nf][0], acc[(MF0)+j][nf], 0, 0, 0); \
      acc[(MF0)+j][nf] = __builtin_amdgcn_mfma_f32_16x16x32_f16(aF[j][1], bF[nf][1], acc[(MF0)+j][nf], 0, 0, 0); \
    } \
  } \
  __builtin_amdgcn_s_setprio(0); \
  POST; \
  __builtin_amdgcn_s_barrier(); \
}

template <int FUSED>
__global__ __launch_bounds__(512, 2)
void gemm320(const f16* __restrict__ A, const f16* __restrict__ Bt,
             const float* __restrict__ bias, f16* __restrict__ C,
             float* __restrict__ P,
             const float* __restrict__ sx, const float* __restrict__ sw,
             const float* __restrict__ sbias, float* __restrict__ so,
             int sideKind, int gemmN, int N, int K, int ntiles, int aux) {
  __shared__ __align__(16) char ldsbuf[147456];
  char* ldsc = ldsbuf;
  const int tid = threadIdx.x;

  // ---- side blocks: tiny fp32 GEMM layers, no barriers, early exit ----
  if ((int)blockIdx.x >= gemmN) {
    int sb = blockIdx.x - gemmN;
    int idx = sb * 512 + tid;
    if (sideKind == 2) {          // v2b = relu(v1b @ vW2 + vb2): 2x1024, K=1024
      int m = idx >> 10, n = idx & 1023;
      float s = sbias[n];
#pragma unroll 8
      for (int k = 0; k < 1024; ++k)
        s = fmaf(sx[(size_t)m * 1024 + k], sw[(size_t)k * 1024 + n], s);
      so[idx] = s > 0.f ? s : 0.f;
    } else if (sideKind == 3) {   // verb_pred = v2b @ vW3 + vb3: 2x500, K=1024
      if (idx < 1000) {
        int m = idx / 500, n = idx % 500;
        float s = sbias[n];
#pragma unroll 8
        for (int k = 0; k < 1024; ++k)
          s = fmaf(sx[(size_t)m * 1024 + k], sw[(size_t)k * 500 + n], s);
        so[idx] = s;
      }
    }
    return;
  }

  const int wave = tid >> 6, lane = tid & 63;
  const int wm = wave >> 2, wn = wave & 3;       // 2 x 4 wave grid (160 x 64 per wave)
  const int lr = lane & 15, lk = lane >> 4;
  const int c0 = lk ^ (lr & 7), c1 = c0 ^ 4;     // swizzled k-chunk indices
  const int arow = (wm * 160 + lr) * 128;
  const int brow = (wn * 64 + lr) * 128;

  // bijective XCD swizzle over the gemm blocks only (gemmN % 8 == 0 by construction)
  int nwg = gemmN, id = blockIdx.x;
  int qq = nwg >> 3, rr8 = nwg & 7;
  int xcd = id & 7, idx = id >> 3;
  int wg = (xcd < rr8 ? xcd * (qq + 1) : rr8 * (qq + 1) + (xcd - rr8) * qq) + idx;
  const int mtile = wg / ntiles, ntile = wg % ntiles;
  const long m0 = (long)mtile * 320, n0 = (long)ntile * 256;

  // staging lane roles: row-in-8 = lane>>3, chunk = (lane&7) ^ row (pre-swizzled source)
  const int srow = lane >> 3;
  const int schunk = (lane & 7) ^ srow;
  const f16* Aglo = A + (m0 + wave * 16 + srow) * (long)K + schunk * 8;
  const f16* Bglo = Bt + (n0 + wave * 16 + srow) * (long)K + schunk * 8;

  f32x4 acc[10][4] = {};
  f16x8 bF[4][2];

  const int NI = K >> 7;   // iterations: 2 K-tiles of 64 each

  // prologue: B(0), A(0), B(1) staged; B(1) left in flight
  STAGE_B(0, 0); STAGE_B(0, 1);
  STAGE_A0(0); STAGE_A1(0);
  STAGE_B(1, 0); STAGE_B(1, 1);
  WV4;
  __builtin_amdgcn_s_barrier();
  LOADB(0);

  auto run_iter = [&](int i, auto lastTag) {
    constexpr bool LAST = decltype(lastTag)::value;
    PHASE_MF(0, 0, 3, STAGE_A0(2*i+1), ;, ;);
    PHASE_MF(0, 3, 3, STAGE_A1(2*i+1), ;, ;);
    PHASE_MF(0, 6, 2, if constexpr (!LAST) STAGE_B(2*i+2, 0), ;, ;);
    PHASE_MF(0, 8, 2, if constexpr (!LAST) STAGE_B(2*i+2, 1),
             if constexpr (LAST) { WV0; } else { WV4; },
             LOADB(1));
    PHASE_MF(1, 0, 3, if constexpr (!LAST) STAGE_A0(2*i+2), ;, ;);
    PHASE_MF(1, 3, 3, if constexpr (!LAST) STAGE_A1(2*i+2), ;, ;);
    PHASE_MF(1, 6, 2, if constexpr (!LAST) STAGE_B(2*i+3, 0), ;, ;);
    PHASE_MF(1, 8, 2, if constexpr (!LAST) STAGE_B(2*i+3, 1),
             if constexpr (!LAST) { WV4; },
             if constexpr (!LAST) LOADB(0));
  };
#pragma unroll 1
  for (int i = 0; i < NI - 1; ++i) run_iter(i, BoolC<false>{});
  run_iter(NI - 1, BoolC<true>{});

  if (FUSED == 0) {
    // two-half LDS-staged epilogue (160 rows per half), coalesced f16x8 copy-out
    f16* lt = (f16*)ldsc;
#pragma unroll
    for (int half = 0; half < 2; ++half) {
      __syncthreads();
      if (wm == half) {
#pragma unroll
        for (int mf = 0; mf < 10; ++mf) {
#pragma unroll
          for (int nf = 0; nf < 4; ++nf) {
            const int col = wn * 64 + nf * 16 + lr;
            const float bv = bias[n0 + col];
#pragma unroll
            for (int r = 0; r < 4; ++r) {
              const int row = mf * 16 + lk * 4 + r;   // 0..159 local
              float v = acc[mf][nf][r] + bv;
              v = v > 0.f ? v : 0.f;
              lt[row * 256 + (col ^ (((row >> 2) & 3) << 4))] = (f16)v;
            }
          }
        }
      }
      __syncthreads();
      const int r0 = tid >> 5, ch = tid & 31;
#pragma unroll
      for (int p = 0; p < 10; ++p) {
        const int row = p * 16 + r0;
        const int chs = ch ^ (((row >> 2) & 3) << 1);
        f16x8 v = *(const f16x8*)(lt + row * 256 + chs * 8);
        *(f16x8*)(C + (m0 + half * 160 + row) * N + n0 + ch * 8) = v;
      }
    }
  } else {
    float* csum = (float*)ldsc;   // safe: all phases + stages drained
    const int mrel = (mtile & 7) * 320 + wm * 160;
#pragma unroll
    for (int nf = 0; nf < 4; ++nf) {
      const int col = (int)n0 + wn * 64 + nf * 16 + lr;
      const float bv = bias[col];
      float s = 0.f;
#pragma unroll
      for (int mf = 0; mf < 10; ++mf) {
        const int rb = mrel + mf * 16 + lk * 4;
#pragma unroll
        for (int r = 0; r < 4; ++r) {
          float v = acc[mf][nf][r] + bv;
          v = v > 0.f ? v : 0.f;
          if (rb + r < VALID_ROWS) s += v;
        }
      }
      s += __shfl_xor(s, 16);
      s += __shfl_xor(s, 32);
      if (lk == 0) csum[wm * 256 + wn * 64 + nf * 16 + lr] = s;
    }
    __syncthreads();
    for (int t = tid; t < 256; t += 512)
      P[(long)(aux + mtile) * N + n0 + t] = csum[t] + csum[256 + t];
  }
}

// ---------------- g[gi][n] = sum over TPG tiles of P ----------------
__global__ void reduce_g(const float* __restrict__ P, float* __restrict__ g) {
  int idx = blockIdx.x * 256 + threadIdx.x;
  if (idx >= NGROUP * 4096) return;
  int gi = idx >> 12, n = idx & 4095;
  float s = 0.f;
#pragma unroll
  for (int t = 0; t < TPG; ++t) s += P[(size_t)(gi * TPG + t) * 4096 + n];
  g[idx] = s;
}

// ---------------- skinny fp32 GEMM (f-MLP): partial over K-chunks + finalize ----------------
__global__ void skinny_part(const float* __restrict__ X, const float* __restrict__ W,
                            float* __restrict__ P, int K, int N, int kchunk) {
  int n = blockIdx.x * 256 + threadIdx.x;
  int k0 = blockIdx.y * kchunk;
  int k1 = k0 + kchunk;
  if (k1 > K) k1 = K;
  if (n >= N) return;
  float acc[12];
#pragma unroll
  for (int m = 0; m < 12; ++m) acc[m] = 0.f;
#pragma unroll 4
  for (int k = k0; k < k1; ++k) {
    float w = W[(size_t)k * N + n];
#pragma unroll
    for (int m = 0; m < 12; ++m) acc[m] = fmaf(X[(size_t)m * K + k], w, acc[m]);
  }
#pragma unroll
  for (int m = 0; m < 12; ++m) P[((size_t)blockIdx.y * 12 + m) * N + n] = acc[m];
}

template <int RELU>
__global__ void skinny_fin(const float* __restrict__ P, const float* __restrict__ bias,
                           float* __restrict__ dst, int N, int KC) {
  int idx = blockIdx.x * 256 + threadIdx.x;
  if (idx >= 12 * N) return;
  int m = idx / N, n = idx - m * N;
  float s = bias ? bias[n] : 0.f;
  for (int kc = 0; kc < KC; ++kc) s += P[((size_t)kc * 12 + m) * N + n];
  if (RELU) s = s > 0.f ? s : 0.f;
  dst[idx] = s;
}

static inline void skinny(const float* X, const float* W, const float* bias, float* dst,
                          float* sp, int K, int N, int relu, hipStream_t stream) {
  int nx = (N + 255) / 256;
  int KC = 1024 / nx;
  if (KC > 256) KC = 256;
  int kmax = K / 16;
  if (kmax < 1) kmax = 1;
  if (KC > kmax) KC = kmax;
  int kchunk = (K + KC - 1) / KC;
  dim3 g1(nx, KC);
  skinny_part<<<g1, 256, 0, stream>>>(X, W, sp, K, N, kchunk);
  int blocks = (12 * N + 255) / 256;
  if (relu)
    skinny_fin<1><<<blocks, 256, 0, stream>>>(sp, bias, dst, N, KC);
  else
    skinny_fin<0><<<blocks, 256, 0, stream>>>(sp, bias, dst, N, KC);
}

extern "C" void kernel_launch(void* const* d_in, const int* in_sizes, int n_in,
                              void* d_out, int out_size, void* d_ws, size_t ws_size,
                              hipStream_t stream) {
  const float* conv = (const float*)d_in[0];
  const int* verbs = (const int*)d_in[1];
  const int* roles = (const int*)d_in[2];
  const float* verb_emb = (const float*)d_in[3];
  const float* role_emb = (const float*)d_in[4];
  const float* vW1 = (const float*)d_in[5];
  const float* vb1 = (const float*)d_in[6];
  const float* vW2 = (const float*)d_in[7];
  const float* vb2 = (const float*)d_in[8];
  const float* vW3 = (const float*)d_in[9];
  const float* vb3 = (const float*)d_in[10];
  const float* gW1 = (const float*)d_in[11];
  const float* gb1 = (const float*)d_in[12];
  const float* gW2 = (const float*)d_in[13];
  const float* gb2 = (const float*)d_in[14];
  const float* gW3 = (const float*)d_in[15];
  const float* gb3 = (const float*)d_in[16];
  const float* gW4 = (const float*)d_in[17];
  const float* gb4 = (const float*)d_in[18];
  const float* fW1 = (const float*)d_in[19];
  const float* fb1 = (const float*)d_in[20];
  const float* fW2 = (const float*)d_in[21];
  const float* fb2 = (const float*)d_in[22];
  const float* fW3 = (const float*)d_in[23];
  const float* fb3 = (const float*)d_in[24];
  float* out = (float*)d_out;

  char* w = (char*)d_ws;
  auto alloc = [&](size_t bytes) {
    char* p = w;
    w += (bytes + 255) & ~(size_t)255;
    return p;
  };
  f16* W2t = (f16*)alloc((size_t)1024 * 1024 * 2);
  f16* W3t = (f16*)alloc((size_t)2048 * 1024 * 2);
  f16* W4t = (f16*)alloc((size_t)4096 * 2048 * 2);
  float* P4 = (float*)alloc((size_t)NGROUP * TPG * 4096 * 4);
  float* Abuf = (float*)alloc((size_t)2 * 49 * 1024 * 4);
  float* Bbuf = (float*)alloc((size_t)2 * 49 * 1024 * 4);
  float* Qbuf = (float*)alloc((size_t)12 * 1024 * 4);
  float* gbuf = (float*)alloc((size_t)12 * 4096 * 4);
  float* sp = (float*)alloc((size_t)128 * 12 * 4096 * 4);  // f-MLP partials
  float* abP = (float*)alloc((size_t)8 * 98 * 2048 * 4);   // AB partials
  float* vp = (float*)alloc((size_t)64 * 2 * 1024 * 4);    // vW1 partials
  float* f1b = (float*)alloc((size_t)12 * 4096 * 4);
  float* f2b = (float*)alloc((size_t)12 * 2048 * 4);
  float* v1b = (float*)alloc((size_t)2 * 1024 * 4);
  float* v2b = (float*)alloc((size_t)2 * 1024 * 4);

  size_t used = (size_t)(w - (char*)d_ws);
  size_t remain = ws_size > used ? ws_size - used : 0;
  static const int opts[6] = {12, 6, 4, 3, 2, 1};
  int gpc = 1;
  for (int i = 0; i < 6; ++i) {
    size_t need = (size_t)opts[i] * GROUP_ROWS * 4096 * 2 + 4096;  // h1+h2+h3
    if (need <= remain) { gpc = opts[i]; break; }
  }
  f16* h1 = (f16*)alloc((size_t)gpc * GROUP_ROWS * 1024 * 2);
  f16* h2 = (f16*)alloc((size_t)gpc * GROUP_ROWS * 1024 * 2);
  f16* h3 = (f16*)alloc((size_t)gpc * GROUP_ROWS * 2048 * 2);
  int nchunks = NGROUP / gpc;

  // S1: all independent prep in one dispatch
  prep1<<<15472, 256, 0, stream>>>(gW2, gW3, gW4, W2t, W3t, W4t,
                                   conv, gW1, abP,
                                   verb_emb, role_emb, verbs, roles, Qbuf,
                                   vW1, vp);
  // S2: finalize AB + verb layer1
  prep2<<<792, 256, 0, stream>>>(abP, Abuf, Bbuf, vp, vb1, v1b);

  // pairwise MLP in chunks of gpc groups; verb layers 2/3 ride as side blocks
  for (int c = 0; c < nchunks; ++c) {
    int g0 = c * gpc;
    int Mc = gpc * GROUP_ROWS;
    int mt = Mc / 320;                 // 8 tiles per group
    int s2 = (c == 0) ? 4 : 0, s3 = (c == 0) ? 2 : 0;
    build_h1<<<Mc, 256, 0, stream>>>(Abuf, Bbuf, Qbuf, gb1, h1, g0);
    gemm320<0><<<4 * mt + s2, 512, 0, stream>>>(h1, W2t, gb2, h2, nullptr,
                                                v1b, vW2, vb2, v2b, 2, 4 * mt,
                                                1024, 1024, 4, 0);
    gemm320<0><<<8 * mt + s3, 512, 0, stream>>>(h2, W3t, gb3, h3, nullptr,
                                                v2b, vW3, vb3, out, 3, 8 * mt,
                                                2048, 1024, 8, 0);
    gemm320<1><<<16 * mt, 512, 0, stream>>>(h3, W4t, gb4, nullptr, P4,
                                            nullptr, nullptr, nullptr, nullptr, 0, 16 * mt,
                                            4096, 2048, 16, g0 * TPG);
  }
  reduce_g<<<(NGROUP * 4096 + 255) / 256, 256, 0, stream>>>(P4, gbuf);

  // final MLP
  skinny(gbuf, fW1, fb1, f1b, sp, 4096, 4096, 1, stream);
  skinny(f1b, fW2, fb2, f2b, sp, 4096, 2048, 1, stream);
  skinny(f2b, fW3, fb3, out + 1000, sp, 2048, 2000, 0, stream);

  (void)in_sizes; (void)n_in; (void)out_size; (void)ws_size;
}

// Round 11
// 930.247 us; speedup vs baseline: 1.3303x; 1.3303x over previous
//
#include <hip/hip_runtime.h>
#include <cstdint>

typedef _Float16 f16;
typedef f16 f16x8 __attribute__((ext_vector_type(8)));
typedef f16 f16x4 __attribute__((ext_vector_type(4)));
typedef float f32x4 __attribute__((ext_vector_type(4)));

#define GROUP_ROWS 2560   // 2401 padded to 10*256
#define VALID_ROWS 2401
#define TPG 10            // 256-row tiles per group
#define NGROUP 12

template <bool B> struct BoolC { static constexpr bool value = B; };

__device__ __forceinline__ void gll16(const void* g, void* l) {
  __builtin_amdgcn_global_load_lds((const __attribute__((address_space(1))) void*)g,
                                   (__attribute__((address_space(3))) void*)l, 16, 0, 0);
}

// ---------------- merged weight transpose + fp32->fp16 : W[K][N] -> Wt[N][K] ----------------
__global__ void wtrans_all(const float* __restrict__ gW2, const float* __restrict__ gW3,
                           const float* __restrict__ gW4, f16* __restrict__ W2t,
                           f16* __restrict__ W3t, f16* __restrict__ W4t) {
  __shared__ float t[32][33];
  int blk = blockIdx.x;
  const float* W; f16* Wt; int K, N, local;
  if (blk < 1024)      { W = gW2; Wt = W2t; K = 1024; N = 1024; local = blk; }
  else if (blk < 3072) { W = gW3; Wt = W3t; K = 1024; N = 2048; local = blk - 1024; }
  else                 { W = gW4; Wt = W4t; K = 2048; N = 4096; local = blk - 3072; }
  int ntn = N >> 5;
  int k0 = (local / ntn) * 32, n0 = (local % ntn) * 32;
  int tx = threadIdx.x & 31, ty = threadIdx.x >> 5;
#pragma unroll
  for (int j = 0; j < 4; ++j)
    t[ty + j * 8][tx] = W[(size_t)(k0 + ty + j * 8) * N + n0 + tx];
  __syncthreads();
#pragma unroll
  for (int j = 0; j < 4; ++j)
    Wt[(size_t)(n0 + ty + j * 8) * K + k0 + tx] = (f16)t[tx][ty + j * 8];
}

// ---------------- rv[g][e] = verb_emb[verbs[b]][e] * role_emb[roles[g]][e] ----------------
__global__ void build_rv(const float* __restrict__ verb_emb, const float* __restrict__ role_emb,
                         const int* __restrict__ verbs, const int* __restrict__ roles,
                         float* __restrict__ rv) {
  int g = blockIdx.x;
  int b = g / 6;
  int v = verbs[b], ro = roles[g];
  for (int e = threadIdx.x; e < 512; e += 256)
    rv[g * 512 + e] = verb_emb[(size_t)v * 512 + e] * role_emb[(size_t)ro * 512 + e];
}

// ---------------- A/B projection, K-split into 8 chunks ----------------
__global__ void build_AB_part(const float* __restrict__ conv, const float* __restrict__ gW1,
                              float* __restrict__ part) {
  int blk = blockIdx.x;
  int nq = blk & 3, bp = blk >> 2;
  int p = bp % 49, b = bp / 49;
  int n = nq * 256 + threadIdx.x;
  int ky = blockIdx.y;
  int k0 = ky * 66, k1 = k0 + 66;
  if (k1 > 514) k1 = 514;
  float accA = 0.f, accB = 0.f;
  for (int k = k0; k < k1; ++k) {
    float s;
    if (k < 512) s = conv[((size_t)b * 512 + k) * 49 + p];
    else {
      int c7 = (k == 512) ? (p % 7) : (p / 7);
      s = (float)(c7 - 3) * (4.0f / 3.0f);
    }
    accA = fmaf(s, gW1[(size_t)k * 1024 + n], accA);
    accB = fmaf(s, gW1[(size_t)(514 + k) * 1024 + n], accB);
  }
  size_t base = ((size_t)ky * 98 + bp) * 2048;
  part[base + n] = accA;
  part[base + 1024 + n] = accB;
}

__global__ void build_AB_fin(const float* __restrict__ part, float* __restrict__ A,
                             float* __restrict__ Bm) {
  int idx = blockIdx.x * 256 + threadIdx.x;
  if (idx >= 98 * 2048) return;
  int bp = idx >> 11, rem = idx & 2047;
  float s = 0.f;
#pragma unroll
  for (int ky = 0; ky < 8; ++ky) s += part[((size_t)ky * 98 + bp) * 2048 + rem];
  if (rem < 1024) A[(size_t)bp * 1024 + rem] = s;
  else Bm[(size_t)bp * 1024 + (rem - 1024)] = s;
}

// ---------------- h1: 2 rows per block, f16x8 stores ----------------
__global__ void build_h1(const float* __restrict__ A, const float* __restrict__ Bm,
                         const float* __restrict__ Q, const float* __restrict__ gb1,
                         f16* __restrict__ h1, int g0) {
  int rc = blockIdx.x * 2 + (threadIdx.x >> 7);
  int lane = threadIdx.x & 127;
  int gl = rc / GROUP_ROWS;
  int li = rc % GROUP_ROWS;
  int g = g0 + gl;
  int b = g / 6;
  int kk = lane * 8;
  f16x8* dst = (f16x8*)(h1 + (size_t)rc * 1024 + kk);
  if (li >= VALID_ROWS) {
    f16x8 z = {};
    *dst = z;
    return;
  }
  int i = li / 49, j = li % 49;
  const float* pa = A + ((size_t)b * 49 + j) * 1024 + kk;
  const float* pb = Bm + ((size_t)b * 49 + i) * 1024 + kk;
  const float* pq = Q + (size_t)g * 1024 + kk;
  const float* pg = gb1 + kk;
  f16x8 r;
#pragma unroll
  for (int h = 0; h < 2; ++h) {
    const float4 a = *(const float4*)(pa + h * 4);
    const float4 bb = *(const float4*)(pb + h * 4);
    const float4 q = *(const float4*)(pq + h * 4);
    const float4 bi = *(const float4*)(pg + h * 4);
    float v0 = a.x + bb.x + q.x + bi.x;
    float v1 = a.y + bb.y + q.y + bi.y;
    float v2 = a.z + bb.z + q.z + bi.z;
    float v3 = a.w + bb.w + q.w + bi.w;
    r[h * 4 + 0] = (f16)(v0 > 0.f ? v0 : 0.f);
    r[h * 4 + 1] = (f16)(v1 > 0.f ? v1 : 0.f);
    r[h * 4 + 2] = (f16)(v2 > 0.f ? v2 : 0.f);
    r[h * 4 + 3] = (f16)(v3 > 0.f ? v3 : 0.f);
  }
  *dst = r;
}

// ================= 256x256 8-phase fp16 MFMA GEMM (round-5 known-good) =================
#define WV4 asm volatile("s_waitcnt vmcnt(4)" ::: "memory")
#define WV0 asm volatile("s_waitcnt vmcnt(0)" ::: "memory")

#define LDSA(buf, mf, cc) (*(const f16x8*)(ldsc + (buf)*32768 + arow + (mf)*2048 + (cc)*16))
#define LDSB(buf, nf, cc) (*(const f16x8*)(ldsc + 65536 + (buf)*32768 + brow + (nf)*2048 + (cc)*16))

#define LOADB(BF, buf) { \
  BF[0][0] = LDSB(buf, 0, c0); BF[0][1] = LDSB(buf, 0, c1); \
  BF[1][0] = LDSB(buf, 1, c0); BF[1][1] = LDSB(buf, 1, c1); \
  BF[2][0] = LDSB(buf, 2, c0); BF[2][1] = LDSB(buf, 2, c1); \
  BF[3][0] = LDSB(buf, 3, c0); BF[3][1] = LDSB(buf, 3, c1); }

#define STAGE_A(t, h) { \
  const f16* _g = Aglo + (long)(h) * (128L * K) + (long)(t) * 64; \
  char* _l = ldsc + ((t)&1)*32768 + ((h)*128 + wave*16)*128; \
  gll16(_g, _l); gll16(_g + 8L*K, _l + 1024); }

#define STAGE_B(t, h) { \
  const f16* _g = Bglo + (long)(h) * (128L * K) + (long)(t) * 64; \
  char* _l = ldsc + 65536 + ((t)&1)*32768 + ((h)*128 + wave*16)*128; \
  gll16(_g, _l); gll16(_g + 8L*K, _l + 1024); }

#define PHASE(q, buf, BF, STG, WT, POST) { \
  f16x8 a00 = LDSA(buf, 2*(q), c0);   f16x8 a01 = LDSA(buf, 2*(q), c1); \
  f16x8 a10 = LDSA(buf, 2*(q)+1, c0); f16x8 a11 = LDSA(buf, 2*(q)+1, c1); \
  STG; \
  WT; \
  __builtin_amdgcn_s_barrier(); \
  __builtin_amdgcn_s_setprio(1); \
  _Pragma("unroll") \
  for (int nf = 0; nf < 4; ++nf) { \
    acc[2*(q)][nf]   = __builtin_amdgcn_mfma_f32_16x16x32_f16(a00, BF[nf][0], acc[2*(q)][nf], 0, 0, 0); \
    acc[2*(q)][nf]   = __builtin_amdgcn_mfma_f32_16x16x32_f16(a01, BF[nf][1], acc[2*(q)][nf], 0, 0, 0); \
    acc[2*(q)+1][nf] = __builtin_amdgcn_mfma_f32_16x16x32_f16(a10, BF[nf][0], acc[2*(q)+1][nf], 0, 0, 0); \
    acc[2*(q)+1][nf] = __builtin_amdgcn_mfma_f32_16x16x32_f16(a11, BF[nf][1], acc[2*(q)+1][nf], 0, 0, 0); \
  } \
  __builtin_amdgcn_s_setprio(0); \
  POST; \
  __builtin_amdgcn_s_barrier(); \
}

template <int FUSED>
__global__ __launch_bounds__(512, 2)
void gemm256(const f16* __restrict__ A, const f16* __restrict__ Bt,
             const float* __restrict__ bias, f16* __restrict__ C,
             float* __restrict__ P, int N, int K, int ntiles, int mtile_off) {
  __shared__ __align__(16) char ldsbuf[131072];
  char* ldsc = ldsbuf;
  const int tid = threadIdx.x;
  const int wave = tid >> 6, lane = tid & 63;
  const int wm = wave >> 2, wn = wave & 3;       // 2 x 4 wave grid
  const int lr = lane & 15, lk = lane >> 4;
  const int c0 = lk ^ (lr & 7), c1 = c0 ^ 4;     // swizzled k-chunk indices
  const int arow = (wm * 128 + lr) * 128;
  const int brow = (wn * 64 + lr) * 128;

  // bijective XCD swizzle, m-major (consecutive wg share A-panel)
  int nwg = gridDim.x, id = blockIdx.x;
  int qq = nwg >> 3, rr8 = nwg & 7;
  int xcd = id & 7, idx = id >> 3;
  int wg = (xcd < rr8 ? xcd * (qq + 1) : rr8 * (qq + 1) + (xcd - rr8) * qq) + idx;
  const int mtile = wg / ntiles, ntile = wg % ntiles;
  const long m0 = (long)mtile * 256, n0 = (long)ntile * 256;

  // staging lane roles: row-in-8 = lane>>3, chunk = (lane&7) ^ row (pre-swizzled source)
  const int srow = lane >> 3;
  const int schunk = (lane & 7) ^ srow;
  const f16* Aglo = A + (m0 + wave * 16 + srow) * (long)K + schunk * 8;
  const f16* Bglo = Bt + (n0 + wave * 16 + srow) * (long)K + schunk * 8;

  f32x4 acc[8][4] = {};
  f16x8 bFa[4][2], bFb[4][2];

  const int NI = K >> 7;   // iterations: 2 K-tiles of 64 each

  // prologue: B(0), A(0), B(1) staged; B(1) allowed in flight
  STAGE_B(0, 0); STAGE_B(0, 1);
  STAGE_A(0, 0); STAGE_A(0, 1);
  STAGE_B(1, 0); STAGE_B(1, 1);
  WV4;
  __builtin_amdgcn_s_barrier();
  LOADB(bFa, 0);

  auto run_iter = [&](int i, auto lastTag) {
    constexpr bool LAST = decltype(lastTag)::value;
    PHASE(0, 0, bFa, STAGE_A(2*i+1, 0), ;, ;);
    PHASE(1, 0, bFa, STAGE_A(2*i+1, 1), ;, ;);
    PHASE(2, 0, bFa, if constexpr (!LAST) STAGE_B(2*i+2, 0), ;, ;);
    PHASE(3, 0, bFa, if constexpr (!LAST) STAGE_B(2*i+2, 1),
                 if constexpr (LAST) { WV0; } else { WV4; },
                 LOADB(bFb, 1));
    PHASE(0, 1, bFb, if constexpr (!LAST) STAGE_A(2*i+2, 0), ;, ;);
    PHASE(1, 1, bFb, if constexpr (!LAST) STAGE_A(2*i+2, 1), ;, ;);
    PHASE(2, 1, bFb, if constexpr (!LAST) STAGE_B(2*i+3, 0), ;, ;);
    PHASE(3, 1, bFb, if constexpr (!LAST) STAGE_B(2*i+3, 1),
                 if constexpr (!LAST) { WV4; },
                 if constexpr (!LAST) LOADB(bFa, 0));
  };
#pragma unroll 1
  for (int i = 0; i < NI - 1; ++i) run_iter(i, BoolC<false>{});
  run_iter(NI - 1, BoolC<true>{});

  if (FUSED == 0) {
    // stage relu(acc+bias) as f16 tile in LDS (col XOR-swizzled), coalesced copy-out
    __syncthreads();
    f16* lt = (f16*)ldsc;
#pragma unroll
    for (int mf = 0; mf < 8; ++mf) {
#pragma unroll
      for (int nf = 0; nf < 4; ++nf) {
        const int col = wn * 64 + nf * 16 + lr;
        const float bv = bias[n0 + col];
#pragma unroll
        for (int r = 0; r < 4; ++r) {
          const int row = wm * 128 + mf * 16 + lk * 4 + r;
          float v = acc[mf][nf][r] + bv;
          v = v > 0.f ? v : 0.f;
          lt[row * 256 + (col ^ (((row >> 2) & 3) << 4))] = (f16)v;
        }
      }
    }
    __syncthreads();
    const int r0 = tid >> 5, ch = tid & 31;
#pragma unroll
    for (int p = 0; p < 16; ++p) {
      const int row = p * 16 + r0;
      const int chs = ch ^ (((row >> 2) & 3) << 1);
      f16x8 v = *(const f16x8*)(lt + row * 256 + chs * 8);
      *(f16x8*)(C + (m0 + row) * N + n0 + ch * 8) = v;
    }
  } else {
    float* csum = (float*)ldsc;   // safe: all phases + stages drained
    const int mrel = (mtile % TPG) * 256 + wm * 128;
#pragma unroll
    for (int nf = 0; nf < 4; ++nf) {
      const int col = (int)n0 + wn * 64 + nf * 16 + lr;
      const float bv = bias[col];
      float s = 0.f;
#pragma unroll
      for (int mf = 0; mf < 8; ++mf) {
        const int rb = mrel + mf * 16 + lk * 4;
#pragma unroll
        for (int r = 0; r < 4; ++r) {
          float v = acc[mf][nf][r] + bv;
          v = v > 0.f ? v : 0.f;
          if (rb + r < VALID_ROWS) s += v;
        }
      }
      s += __shfl_xor(s, 16);
      s += __shfl_xor(s, 32);
      if (lk == 0) csum[wm * 256 + wn * 64 + nf * 16 + lr] = s;
    }
    __syncthreads();
    for (int t = tid; t < 256; t += 512)
      P[(long)(mtile_off + mtile) * N + n0 + t] = csum[t] + csum[256 + t];
  }
}

// ---------------- g[gi][n] = sum over TPG tiles of P ----------------
__global__ void reduce_g(const float* __restrict__ P, float* __restrict__ g) {
  int idx = blockIdx.x * 256 + threadIdx.x;
  if (idx >= NGROUP * 4096) return;
  int gi = idx >> 12, n = idx & 4095;
  float s = 0.f;
#pragma unroll
  for (int t = 0; t < TPG; ++t) s += P[(size_t)(gi * TPG + t) * 4096 + n];
  g[idx] = s;
}

// ---------------- skinny fp32 GEMM: partial over K-chunks + finalize ----------------
template <int M>
__global__ void skinny_part(const float* __restrict__ X, const float* __restrict__ W,
                            float* __restrict__ P, int K, int N, int kchunk) {
  int n = blockIdx.x * 256 + threadIdx.x;
  int k0 = blockIdx.y * kchunk;
  int k1 = k0 + kchunk;
  if (k1 > K) k1 = K;
  if (n >= N) return;
  float acc[M];
#pragma unroll
  for (int m = 0; m < M; ++m) acc[m] = 0.f;
#pragma unroll 4
  for (int k = k0; k < k1; ++k) {
    float w = W[(size_t)k * N + n];
#pragma unroll
    for (int m = 0; m < M; ++m) acc[m] = fmaf(X[(size_t)m * K + k], w, acc[m]);
  }
#pragma unroll
  for (int m = 0; m < M; ++m) P[((size_t)blockIdx.y * M + m) * N + n] = acc[m];
}

template <int RELU>
__global__ void skinny_fin(const float* __restrict__ P, const float* __restrict__ bias,
                           float* __restrict__ dst, int M, int N, int KC) {
  int idx = blockIdx.x * 256 + threadIdx.x;
  if (idx >= M * N) return;
  int m = idx / N, n = idx - m * N;
  float s = bias ? bias[n] : 0.f;
  for (int kc = 0; kc < KC; ++kc) s += P[((size_t)kc * M + m) * N + n];
  if (RELU) s = s > 0.f ? s : 0.f;
  dst[idx] = s;
}

// ---------------- host ----------------
static inline void skinny(const float* X, const float* W, const float* bias, float* dst,
                          float* sp, int Mrows, int K, int N, int relu, hipStream_t stream) {
  int nx = (N + 255) / 256;
  int KC = 1024 / nx;
  if (KC > 256) KC = 256;
  int kmax = K / 16;
  if (kmax < 1) kmax = 1;
  if (KC > kmax) KC = kmax;
  int kchunk = (K + KC - 1) / KC;
  dim3 g1(nx, KC);
  if (Mrows == 2)
    skinny_part<2><<<g1, 256, 0, stream>>>(X, W, sp, K, N, kchunk);
  else
    skinny_part<12><<<g1, 256, 0, stream>>>(X, W, sp, K, N, kchunk);
  int blocks = (Mrows * N + 255) / 256;
  if (relu)
    skinny_fin<1><<<blocks, 256, 0, stream>>>(sp, bias, dst, Mrows, N, KC);
  else
    skinny_fin<0><<<blocks, 256, 0, stream>>>(sp, bias, dst, Mrows, N, KC);
}

extern "C" void kernel_launch(void* const* d_in, const int* in_sizes, int n_in,
                              void* d_out, int out_size, void* d_ws, size_t ws_size,
                              hipStream_t stream) {
  const float* conv = (const float*)d_in[0];
  const int* verbs = (const int*)d_in[1];
  const int* roles = (const int*)d_in[2];
  const float* verb_emb = (const float*)d_in[3];
  const float* role_emb = (const float*)d_in[4];
  const float* vW1 = (const float*)d_in[5];
  const float* vb1 = (const float*)d_in[6];
  const float* vW2 = (const float*)d_in[7];
  const float* vb2 = (const float*)d_in[8];
  const float* vW3 = (const float*)d_in[9];
  const float* vb3 = (const float*)d_in[10];
  const float* gW1 = (const float*)d_in[11];
  const float* gb1 = (const float*)d_in[12];
  const float* gW2 = (const float*)d_in[13];
  const float* gb2 = (const float*)d_in[14];
  const float* gW3 = (const float*)d_in[15];
  const float* gb3 = (const float*)d_in[16];
  const float* gW4 = (const float*)d_in[17];
  const float* gb4 = (const float*)d_in[18];
  const float* fW1 = (const float*)d_in[19];
  const float* fb1 = (const float*)d_in[20];
  const float* fW2 = (const float*)d_in[21];
  const float* fb2 = (const float*)d_in[22];
  const float* fW3 = (const float*)d_in[23];
  const float* fb3 = (const float*)d_in[24];
  float* out = (float*)d_out;

  char* w = (char*)d_ws;
  auto alloc = [&](size_t bytes) {
    char* p = w;
    w += (bytes + 255) & ~(size_t)255;
    return p;
  };
  f16* W2t = (f16*)alloc((size_t)1024 * 1024 * 2);
  f16* W3t = (f16*)alloc((size_t)2048 * 1024 * 2);
  f16* W4t = (f16*)alloc((size_t)4096 * 2048 * 2);
  float* P4 = (float*)alloc((size_t)NGROUP * TPG * 4096 * 4);
  float* Abuf = (float*)alloc((size_t)2 * 49 * 1024 * 4);
  float* Bbuf = (float*)alloc((size_t)2 * 49 * 1024 * 4);
  float* Qbuf = (float*)alloc((size_t)12 * 1024 * 4);
  float* rvb = (float*)alloc((size_t)12 * 512 * 4);
  float* gbuf = (float*)alloc((size_t)12 * 4096 * 4);
  float* sp = (float*)alloc((size_t)64 * 12 * 4096 * 4);   // also holds AB partials
  float* f1b = (float*)alloc((size_t)12 * 4096 * 4);
  float* f2b = (float*)alloc((size_t)12 * 2048 * 4);
  float* v1b = (float*)alloc((size_t)2 * 1024 * 4);
  float* v2b = (float*)alloc((size_t)2 * 1024 * 4);

  size_t used = (size_t)(w - (char*)d_ws);
  size_t remain = ws_size > used ? ws_size - used : 0;
  static const int opts[6] = {12, 6, 4, 3, 2, 1};
  int gpc = 1;
  for (int i = 0; i < 6; ++i) {
    size_t need = (size_t)opts[i] * GROUP_ROWS * 4096 * 2 + 4096;
    if (need <= remain) { gpc = opts[i]; break; }
  }
  f16* h1 = (f16*)alloc((size_t)gpc * GROUP_ROWS * 1024 * 2);
  f16* h2 = (f16*)alloc((size_t)gpc * GROUP_ROWS * 1024 * 2);
  f16* h3 = (f16*)alloc((size_t)gpc * GROUP_ROWS * 2048 * 2);
  int nchunks = NGROUP / gpc;

  // weight prep (one merged dispatch)
  wtrans_all<<<1024 + 2048 + 8192, 256, 0, stream>>>(gW2, gW3, gW4, W2t, W3t, W4t);

  // small projections (AB partials live in sp, consumed by fin before skinny reuses sp)
  build_rv<<<12, 256, 0, stream>>>(verb_emb, role_emb, verbs, roles, rvb);
  build_AB_part<<<dim3(98 * 4, 8), 256, 0, stream>>>(conv, gW1, sp);
  build_AB_fin<<<(98 * 2048 + 255) / 256, 256, 0, stream>>>(sp, Abuf, Bbuf);
  skinny(rvb, gW1 + (size_t)1028 * 1024, nullptr, Qbuf, sp, 12, 512, 1024, 0, stream);

  // verb branch (fp32 exact)
  skinny(conv, vW1, vb1, v1b, sp, 2, 25088, 1024, 1, stream);
  skinny(v1b, vW2, vb2, v2b, sp, 2, 1024, 1024, 1, stream);
  skinny(v2b, vW3, vb3, out, sp, 2, 1024, 500, 0, stream);

  // pairwise MLP in chunks of gpc groups
  for (int c = 0; c < nchunks; ++c) {
    int g0 = c * gpc;
    int Mc = gpc * GROUP_ROWS;
    int mt = Mc / 256;
    build_h1<<<Mc / 2, 256, 0, stream>>>(Abuf, Bbuf, Qbuf, gb1, h1, g0);
    gemm256<0><<<4 * mt, 512, 0, stream>>>(h1, W2t, gb2, h2, nullptr, 1024, 1024, 4, 0);
    gemm256<0><<<8 * mt, 512, 0, stream>>>(h2, W3t, gb3, h3, nullptr, 2048, 1024, 8, 0);
    gemm256<1><<<16 * mt, 512, 0, stream>>>(h3, W4t, gb4, nullptr, P4, 4096, 2048, 16, g0 * TPG);
  }
  reduce_g<<<(NGROUP * 4096 + 255) / 256, 256, 0, stream>>>(P4, gbuf);

  // final MLP
  skinny(gbuf, fW1, fb1, f1b, sp, 12, 4096, 4096, 1, stream);
  skinny(f1b, fW2, fb2, f2b, sp, 12, 4096, 2048, 1, stream);
  skinny(f2b, fW3, fb3, out + 1000, sp, 12, 2048, 2000, 0, stream);

  (void)in_sizes; (void)n_in; (void)out_size; (void)ws_size;
}